// Round 5
// baseline (645.552 us; speedup 1.0000x reference)
//
#include <hip/hip_runtime.h>
#include <math.h>

// Problem dims (fixed by the reference setup): B=4, C=64, H=512, W=512, fp32.
#define HH 512
#define WW 512
#define W4 128          // float4s per row
#define IMG (HH * WW)

typedef float f32x4 __attribute__((ext_vector_type(4)));

__device__ __forceinline__ f32x4 bc4(float v) { f32x4 r = {v, v, v, v}; return r; }

template<bool CLAMP>
__device__ __forceinline__ void compute_tile(const f32x4* __restrict__ img4,
                                             f32x4* __restrict__ out4,
                                             int h0, int q,
                                             float s0, float s1, float s2, float m4c)
{
    auto ld = [&](int r) -> f32x4 {
        const int rr = CLAMP ? (r < 0 ? 0 : (r > HH - 1 ? HH - 1 : r)) : r;
        return img4[rr * W4 + q];
    };

    // Vertical row set for 4 output rows h0..h0+3 (all aligned float4 at col q).
    f32x4 C[6];                       // rows h0-1 .. h0+4 (d=1 + reuse for d=4)
#pragma unroll
    for (int k = 0; k < 6; ++k) C[k] = ld(h0 - 1 + k);
    f32x4 U4[3], D4[3];               // d=4: h0-4..h0-2 and h0+5..h0+7
#pragma unroll
    for (int k = 0; k < 3; ++k) U4[k] = ld(h0 - 4 + k);
#pragma unroll
    for (int k = 0; k < 3; ++k) D4[k] = ld(h0 + 5 + k);
    f32x4 U16[4], D16[4];             // d=16: h0-16..h0-13 and h0+16..h0+19
#pragma unroll
    for (int k = 0; k < 4; ++k) U16[k] = ld(h0 - 16 + k);
#pragma unroll
    for (int k = 0; k < 4; ++k) D16[k] = ld(h0 + 16 + k);

    // Horizontal quad indices / boundary predicates.
    const int qm1 = max(q - 1, 0), qp1 = min(q + 1, W4 - 1);
    const int qm4 = max(q - 4, 0), qp4 = min(q + 4, W4 - 1);
    const bool pl4 = (q == 0), pr4 = (q == W4 - 1);
    const bool pl16 = (q < 4), pr16 = (q > W4 - 5);

#pragma unroll
    for (int r = 0; r < 4; ++r) {
        const int rr = h0 + r;                      // always in [0,511]
        const f32x4* __restrict__ rowq = img4 + rr * W4;

        f32x4 l4 = rowq[qm1];  if (pl4)  l4 = bc4(l4.x);
        f32x4 r4 = rowq[qp1];  if (pr4)  r4 = bc4(r4.w);
        f32x4 l16 = rowq[qm4]; if (pl16) l16 = bc4(l16.x);
        f32x4 r16 = rowq[qp4]; if (pr16) r16 = bc4(r16.w);

        const f32x4 cc  = C[r + 1];
        const f32x4 up1 = C[r], dn1 = C[r + 2];
        const f32x4 up4 = (r < 3) ? U4[r] : C[0];
        const f32x4 dn4 = (r == 0) ? C[5] : D4[r - 1];
        const f32x4 u16v = U16[r], d16v = D16[r];

        // d=1 horizontal: neighbors from center regs + l4.w / r4.x
        f32x4 l1 = { l4.w, cc.x, cc.y, cc.z };
        f32x4 r1 = { cc.y, cc.z, cc.w, r4.x };

        const f32x4 d1s  = (up1 + dn1) + (l1 + r1);
        const f32x4 d4s  = (up4 + dn4) + (l4 + r4);
        const f32x4 d16s = (u16v + d16v) + (l16 + r16);

        f32x4 o;
#pragma unroll
        for (int j = 0; j < 4; ++j) {
            float acc = m4c * cc[j];
            acc = fmaf(s0, d1s[j], acc);
            acc = fmaf(s1, d4s[j], acc);
            acc = fmaf(s2, d16s[j], acc);
            o[j] = acc;
        }
        __builtin_nontemporal_store(o, out4 + rr * W4 + q);
    }
}

__global__ __launch_bounds__(256, 8) void lap3_kernel(const float* __restrict__ u,
                                                      const float* __restrict__ D,
                                                      float* __restrict__ out) {
    // 2048 persistent-ish blocks = exactly 8 blocks/CU (32 waves/CU @ 52 VGPR).
    // Chunked XCD swizzle: XCD k owns chunks [k*256, (k+1)*256) -> contiguous
    // row bands, so all vertical halos stay in that XCD's private L2.
    const int bid = blockIdx.x;
    const int chunk = (bid & 7) * 256 + (bid >> 3);   // 0..2047
    const int bc   = chunk >> 3;                      // image (b*64+c), 0..255
    const int band = chunk & 7;                       // 64-row band within image
    const int c    = bc & 63;

    // softplus once per block (bc uniform across the whole block)
    const float x0 = D[c], x1 = D[64 + c], x2 = D[128 + c];
    const float s0 = fmaxf(x0, 0.0f) + log1pf(expf(-fabsf(x0)));
    const float s1 = fmaxf(x1, 0.0f) + log1pf(expf(-fabsf(x1)));
    const float s2 = fmaxf(x2, 0.0f) + log1pf(expf(-fabsf(x2)));
    const float m4c = -4.0f * (s0 + s1 + s2);

    const int q   = threadIdx.x & 127;     // quad column
    const int sub = threadIdx.x >> 7;      // 0/1: which 4-row half of the 8-row step

    const f32x4* img4 = reinterpret_cast<const f32x4*>(u) + (size_t)bc * (IMG / 4);
    f32x4* out4 = reinterpret_cast<f32x4*>(out) + (size_t)bc * (IMG / 4);

    const int hbase = band * 64 + sub * 4;

    if (band >= 1 && band <= 6) {
        // whole band is interior: rows 48..463 need h0 in [16,492] -> always true
#pragma unroll 2
        for (int i = 0; i < 8; ++i)
            compute_tile<false>(img4, out4, hbase + i * 8, q, s0, s1, s2, m4c);
    } else {
#pragma unroll 1
        for (int i = 0; i < 8; ++i) {
            const int h0 = hbase + i * 8;
            if (h0 >= 16 && h0 <= HH - 20)
                compute_tile<false>(img4, out4, h0, q, s0, s1, s2, m4c);
            else
                compute_tile<true>(img4, out4, h0, q, s0, s1, s2, m4c);
        }
    }
}

extern "C" void kernel_launch(void* const* d_in, const int* in_sizes, int n_in,
                              void* d_out, int out_size, void* d_ws, size_t ws_size,
                              hipStream_t stream) {
    const float* u = (const float*)d_in[0];
    const float* D = (const float*)d_in[1];
    float* out = (float*)d_out;

    lap3_kernel<<<2048, 256, 0, stream>>>(u, D, out);
}

// Round 6
// 105.823 us; speedup vs baseline: 6.1003x; 6.1003x over previous
//
#include <hip/hip_runtime.h>
#include <math.h>

// Problem dims (fixed by the reference setup): B=4, C=64, H=512, W=512, fp32.
#define HH 512
#define WW 512
#define W4 128          // float4s per row
#define IMG (HH * WW)

typedef float f32x4 __attribute__((ext_vector_type(4)));

__device__ __forceinline__ f32x4 bc4(float v) { f32x4 r = {v, v, v, v}; return r; }

__device__ __forceinline__ float softplus(float x) {
    return fmaxf(x, 0.0f) + log1pf(expf(-fabsf(x)));
}

template<bool CLAMP>
__device__ __forceinline__ void compute_tile(const f32x4* __restrict__ img4,
                                             f32x4* __restrict__ out4,
                                             int h0, int q,
                                             float s0, float s1, float s2, float m4c)
{
    auto ld = [&](int r) -> f32x4 {
        const int rr = CLAMP ? (r < 0 ? 0 : (r > HH - 1 ? HH - 1 : r)) : r;
        return img4[rr * W4 + q];
    };

    // Vertical row set for 4 output rows h0..h0+3 (all aligned float4 at col q).
    f32x4 C[6];                       // rows h0-1 .. h0+4 (d=1 + reuse for d=4)
#pragma unroll
    for (int k = 0; k < 6; ++k) C[k] = ld(h0 - 1 + k);
    f32x4 U4[3], D4[3];               // d=4: h0-4..h0-2 and h0+5..h0+7
#pragma unroll
    for (int k = 0; k < 3; ++k) U4[k] = ld(h0 - 4 + k);
#pragma unroll
    for (int k = 0; k < 3; ++k) D4[k] = ld(h0 + 5 + k);
    f32x4 U16[4], D16[4];             // d=16: h0-16..h0-13 and h0+16..h0+19
#pragma unroll
    for (int k = 0; k < 4; ++k) U16[k] = ld(h0 - 16 + k);
#pragma unroll
    for (int k = 0; k < 4; ++k) D16[k] = ld(h0 + 16 + k);

    // Horizontal quad indices / boundary predicates.
    const int qm1 = max(q - 1, 0), qp1 = min(q + 1, W4 - 1);
    const int qm4 = max(q - 4, 0), qp4 = min(q + 4, W4 - 1);
    const bool pl4 = (q == 0), pr4 = (q == W4 - 1);
    const bool pl16 = (q < 4), pr16 = (q > W4 - 5);

#pragma unroll
    for (int r = 0; r < 4; ++r) {
        const int rr = h0 + r;                      // always in [0,511]
        const f32x4* __restrict__ rowq = img4 + rr * W4;

        f32x4 l4 = rowq[qm1];  if (pl4)  l4 = bc4(l4.x);
        f32x4 r4 = rowq[qp1];  if (pr4)  r4 = bc4(r4.w);
        f32x4 l16 = rowq[qm4]; if (pl16) l16 = bc4(l16.x);
        f32x4 r16 = rowq[qp4]; if (pr16) r16 = bc4(r16.w);

        const f32x4 cc  = C[r + 1];
        const f32x4 up1 = C[r], dn1 = C[r + 2];
        const f32x4 up4 = (r < 3) ? U4[r] : C[0];
        const f32x4 dn4 = (r == 0) ? C[5] : D4[r - 1];
        const f32x4 u16v = U16[r], d16v = D16[r];

        // d=1 horizontal: neighbors from center regs + l4.w / r4.x
        f32x4 l1 = { l4.w, cc.x, cc.y, cc.z };
        f32x4 r1 = { cc.y, cc.z, cc.w, r4.x };

        const f32x4 d1s  = (up1 + dn1) + (l1 + r1);
        const f32x4 d4s  = (up4 + dn4) + (l4 + r4);
        const f32x4 d16s = (u16v + d16v) + (l16 + r16);

        f32x4 o;
#pragma unroll
        for (int j = 0; j < 4; ++j) {
            float acc = m4c * cc[j];
            acc = fmaf(s0, d1s[j], acc);
            acc = fmaf(s1, d4s[j], acc);
            acc = fmaf(s2, d16s[j], acc);
            o[j] = acc;
        }
        __builtin_nontemporal_store(o, out4 + rr * W4 + q);
    }
}

__global__ __launch_bounds__(256) void lap3_kernel(const float* __restrict__ u,
                                                   const float* __restrict__ D,
                                                   float* __restrict__ out) {
    // Persistent sweep: 2048 blocks (8 per CU). Strip = 8 consecutive rows of
    // one image (16384 strips total). Block b handles strips b' + it*2048, so
    // at each iteration the 2048 in-flight strips form ONE contiguous 32 MB
    // window (R4's locality), while all CUs stay fully resident (R5's
    // occupancy). Chunked swizzle: XCD k's 256 blocks own a contiguous
    // 256-strip (4 MB) band inside that window -> halos hit its private L2.
    const int bid = blockIdx.x;
    const int b2  = (bid & 7) * 256 + (bid >> 3);   // bijective on [0,2048)
    const int q   = threadIdx.x & 127;              // quad column
    const int sub = threadIdx.x >> 7;               // which 4-row half of strip

    // Image index alternates between two channels across iterations
    // (2048 strips = exactly 32 images): c = (b2>>6) + 32*it (mod 64).
    const int c0 = (b2 >> 6) & 63;
    const int c1 = (c0 + 32) & 63;
    const float sA0 = softplus(D[c0]), sA1 = softplus(D[64 + c0]), sA2 = softplus(D[128 + c0]);
    const float sB0 = softplus(D[c1]), sB1 = softplus(D[64 + c1]), sB2 = softplus(D[128 + c1]);

#pragma unroll 1
    for (int it = 0; it < 8; ++it) {
        const int s  = b2 + it * 2048;              // strip 0..16383
        const int bc = s >> 6;                      // image (b*64+c)
        const int h0 = ((s & 63) << 3) + (sub << 2);

        const float t0 = (it & 1) ? sB0 : sA0;
        const float t1 = (it & 1) ? sB1 : sA1;
        const float t2 = (it & 1) ? sB2 : sA2;
        const float m4c = -4.0f * (t0 + t1 + t2);

        const f32x4* img4 = reinterpret_cast<const f32x4*>(u) + (size_t)bc * (IMG / 4);
        f32x4* out4 = reinterpret_cast<f32x4*>(out) + (size_t)bc * (IMG / 4);

        if (h0 >= 16 && h0 <= HH - 20)              // wave-uniform
            compute_tile<false>(img4, out4, h0, q, t0, t1, t2, m4c);
        else
            compute_tile<true>(img4, out4, h0, q, t0, t1, t2, m4c);
    }
}

extern "C" void kernel_launch(void* const* d_in, const int* in_sizes, int n_in,
                              void* d_out, int out_size, void* d_ws, size_t ws_size,
                              hipStream_t stream) {
    const float* u = (const float*)d_in[0];
    const float* D = (const float*)d_in[1];
    float* out = (float*)d_out;

    lap3_kernel<<<2048, 256, 0, stream>>>(u, D, out);
}

// Round 7
// 87.753 us; speedup vs baseline: 7.3565x; 1.2059x over previous
//
#include <hip/hip_runtime.h>
#include <math.h>

// Problem dims (fixed by the reference setup): B=4, C=64, H=512, W=512, fp32.
#define HH 512
#define WW 512
#define W4Q 128          // float4 quads per row
#define IMG (HH * WW)
#define NR 64            // LDS circular window: 64 row slots
#define RST 129          // quads per slot (+1 quad pad -> breaks bank alignment)
#define SS 32            // rows advanced per step
#define HALF 256         // output rows per block

typedef float f32x4 __attribute__((ext_vector_type(4)));

__device__ __forceinline__ f32x4 bc4(float v) { f32x4 r = {v, v, v, v}; return r; }
__device__ __forceinline__ float softplus(float x) {
    return fmaxf(x, 0.0f) + log1pf(expf(-fabsf(x)));
}

__global__ __launch_bounds__(512, 2) void lap3_kernel(const float* __restrict__ u,
                                                      const float* __restrict__ D,
                                                      float* __restrict__ out) {
    // 132 KB rolling row window (64 rows x 129 quads). One block per CU.
    __shared__ f32x4 lds[NR * RST];

    const int b    = blockIdx.x;        // 512 blocks = 256 images x 2 halves
    const int bc   = b >> 1;            // image index (b*64 + c)
    const int row0 = (b & 1) * HALF;    // output rows [row0, row0+256)
    const int c    = bc & 63;

    const float s0 = softplus(D[c]);
    const float s1 = softplus(D[64 + c]);
    const float s2 = softplus(D[128 + c]);
    const float m4c = -4.0f * (s0 + s1 + s2);

    const int t  = threadIdx.x;
    const int q  = t & 127;             // compute: quad column 0..127
    const int g  = t >> 7;              // compute: row-group 0..3 (8 rows each)
    const int sc = t & 15;              // staging: column group (quads sc+16j)
    const int sr = t >> 4;              // staging: row offset 0..31

    const f32x4* __restrict__ img4 =
        reinterpret_cast<const f32x4*>(u) + (size_t)bc * (IMG / 4);
    f32x4* __restrict__ out4 =
        reinterpret_cast<f32x4*>(out) + (size_t)bc * (IMG / 4);

    // ---- prologue: stage virtual rows [row0-16, row0+47] (clamped at edges).
    // Vertical clamping happens HERE (virtual-row slots hold clamped data),
    // so the compute loop needs no vertical boundary logic at all.
#pragma unroll
    for (int rnd = 0; rnd < 2; ++rnd) {
        const int vrow = row0 - 16 + rnd * 32 + sr;
        const int crow = min(max(vrow, 0), HH - 1);
        const int slot = vrow & (NR - 1);
#pragma unroll
        for (int j = 0; j < 8; ++j) {
            const int qc = sc + 16 * j;
            lds[slot * RST + qc] = img4[crow * W4Q + qc];
        }
    }
    __syncthreads();

    // horizontal boundary handling (same validated scheme as R4)
    const int qm1 = max(q - 1, 0), qp1 = min(q + 1, W4Q - 1);
    const int qm4 = max(q - 4, 0), qp4 = min(q + 4, W4Q - 1);
    const bool pl4 = (q == 0), pr4 = (q == W4Q - 1);
    const bool pl16 = (q < 4), pr16 = (q > W4Q - 5);

#pragma unroll 1
    for (int step = 0; step < HALF / SS; ++step) {
        const int h0 = row0 + step * SS;

        // async-split staging: issue next step's global loads NOW, write to
        // LDS after the post-compute barrier (HBM latency hides under compute)
        f32x4 gbuf[8];
        int nslot = 0;
        const bool do_stage = (step + 1 < HALF / SS);
        if (do_stage) {
            const int vrow = h0 + 48 + sr;            // rows [h0+48, h0+79]
            const int crow = min(vrow, HH - 1);       // only top clamp possible
            nslot = vrow & (NR - 1);
#pragma unroll
            for (int j = 0; j < 8; ++j)
                gbuf[j] = img4[crow * W4Q + sc + 16 * j];
        }

        // ---- compute 8-row column run from LDS
        const int hr = h0 + g * 8;
        f32x4 C[10];                                   // rows hr-1 .. hr+8
#pragma unroll
        for (int k = 0; k < 10; ++k)
            C[k] = lds[((hr - 1 + k) & (NR - 1)) * RST + q];
        f32x4 U4[3], D4v[3];                           // d=4 extras
#pragma unroll
        for (int k = 0; k < 3; ++k)
            U4[k] = lds[((hr - 4 + k) & (NR - 1)) * RST + q];
#pragma unroll
        for (int k = 0; k < 3; ++k)
            D4v[k] = lds[((hr + 9 + k) & (NR - 1)) * RST + q];

#pragma unroll
        for (int r = 0; r < 8; ++r) {
            const int rs = ((hr + r) & (NR - 1)) * RST;
            f32x4 l4 = lds[rs + qm1];  if (pl4)  l4 = bc4(l4.x);
            f32x4 r4 = lds[rs + qp1];  if (pr4)  r4 = bc4(r4.w);
            f32x4 l16 = lds[rs + qm4]; if (pl16) l16 = bc4(l16.x);
            f32x4 r16 = lds[rs + qp4]; if (pr16) r16 = bc4(r16.w);
            const f32x4 u16 = lds[((hr + r - 16) & (NR - 1)) * RST + q];
            const f32x4 d16 = lds[((hr + r + 16) & (NR - 1)) * RST + q];

            const f32x4 cc = C[r + 1], up1 = C[r], dn1 = C[r + 2];
            const f32x4 u4 = (r < 3) ? U4[r] : C[r - 3];     // row hr+r-4
            const f32x4 d4 = (r > 4) ? D4v[r - 5] : C[r + 5];// row hr+r+4

            // d=1 horizontal from registers (l4.w / r4.x are the +/-1 px)
            f32x4 l1 = { l4.w, cc.x, cc.y, cc.z };
            f32x4 r1 = { cc.y, cc.z, cc.w, r4.x };

            const f32x4 d1s  = (up1 + dn1) + (l1 + r1);
            const f32x4 d4s  = (u4 + d4) + (l4 + r4);
            const f32x4 d16s = (u16 + d16) + (l16 + r16);

            f32x4 o;
#pragma unroll
            for (int j = 0; j < 4; ++j) {
                float acc = m4c * cc[j];
                acc = fmaf(s0, d1s[j], acc);
                acc = fmaf(s1, d4s[j], acc);
                acc = fmaf(s2, d16s[j], acc);
                o[j] = acc;
            }
            __builtin_nontemporal_store(o, out4 + (hr + r) * W4Q + q);
        }

        __syncthreads();            // everyone done reading rows we overwrite
        if (do_stage) {
#pragma unroll
            for (int j = 0; j < 8; ++j)
                lds[nslot * RST + sc + 16 * j] = gbuf[j];
        }
        __syncthreads();            // staged rows visible for next step
    }
}

extern "C" void kernel_launch(void* const* d_in, const int* in_sizes, int n_in,
                              void* d_out, int out_size, void* d_ws, size_t ws_size,
                              hipStream_t stream) {
    const float* u = (const float*)d_in[0];
    const float* D = (const float*)d_in[1];
    float* out = (float*)d_out;

    lap3_kernel<<<512, 512, 0, stream>>>(u, D, out);
}